// Round 2
// baseline (263.856 us; speedup 1.0000x reference)
//
#include <hip/hip_runtime.h>
#include <hip/hip_bf16.h>

#define M_DIM 2048   // size
#define K_DIM 2048   // prev_size
#define N_DIM 8192   // batch

typedef __attribute__((ext_vector_type(4))) float f32x4;
typedef __attribute__((ext_vector_type(8))) short s16x8;

static __device__ __forceinline__ ushort f2bf(float x) {
    __hip_bfloat16 h = __float2bfloat16(x);
    return *reinterpret_cast<ushort*>(&h);
}

// async global->LDS, 16B per lane; dst must be wave-uniform base (+lane*16 implicit)
static __device__ __forceinline__ void stage16(const void* g, void* l) {
    __builtin_amdgcn_global_load_lds(
        (const __attribute__((address_space(1))) void*)g,
        (__attribute__((address_space(3))) void*)l, 16, 0, 0);
}

// ---------------- softmax over rows of Wa/Wb -> bf16 probabilities ----------
__global__ __launch_bounds__(256) void softmax_rows_kernel(
    const float* __restrict__ Wa, const float* __restrict__ Wb,
    ushort* __restrict__ Pa, ushort* __restrict__ Pb)
{
    const float* W = blockIdx.y ? Wb : Wa;
    ushort* P = blockIdx.y ? Pb : Pa;
    const int row = blockIdx.x;
    const int t = threadIdx.x;
    const float* w = W + (size_t)row * K_DIM + t * 8;
    float4 v0 = *(const float4*)(w);
    float4 v1 = *(const float4*)(w + 4);
    float x[8] = {v0.x, v0.y, v0.z, v0.w, v1.x, v1.y, v1.z, v1.w};

    float m = x[0];
#pragma unroll
    for (int i = 1; i < 8; ++i) m = fmaxf(m, x[i]);
#pragma unroll
    for (int off = 32; off >= 1; off >>= 1) m = fmaxf(m, __shfl_xor(m, off));
    __shared__ float redm[4], reds[4];
    const int wid = t >> 6;
    if ((t & 63) == 0) redm[wid] = m;
    __syncthreads();
    m = fmaxf(fmaxf(redm[0], redm[1]), fmaxf(redm[2], redm[3]));

    float s = 0.f;
#pragma unroll
    for (int i = 0; i < 8; ++i) { x[i] = __expf(x[i] - m); s += x[i]; }
#pragma unroll
    for (int off = 32; off >= 1; off >>= 1) s += __shfl_xor(s, off);
    if ((t & 63) == 0) reds[wid] = s;
    __syncthreads();
    s = reds[0] + reds[1] + reds[2] + reds[3];
    const float inv = 1.0f / s;

    union { ushort u[8]; int4 v; } pk;
#pragma unroll
    for (int i = 0; i < 8; ++i) pk.u[i] = f2bf(x[i] * inv);
    *(int4*)(P + (size_t)row * K_DIM + t * 8) = pk.v;
}

// ---------- table softmax (over 16) contracted with gate coeffs -> c[4][M] --
__global__ __launch_bounds__(256) void table_c_kernel(
    const float* __restrict__ TW, float4* __restrict__ C4)
{
    const int s = blockIdx.x * 256 + threadIdx.x;
    if (s >= M_DIM) return;
    float x[16];
    float m = -1e30f;
#pragma unroll
    for (int t = 0; t < 16; ++t) { x[t] = TW[t * M_DIM + s]; m = fmaxf(m, x[t]); }
    float sum = 0.f;
#pragma unroll
    for (int t = 0; t < 16; ++t) { x[t] = __expf(x[t] - m); sum += x[t]; }
    const float inv = 1.0f / sum;

    const float c0a[16] = {0,0,0,0,0,0,0,0, 1,1,1,1,1,1,1,1};
    const float cAa[16] = {0,0,1,1,0,0,1,1, -1,-1,0,0,-1,-1,0,0};
    const float cBa[16] = {0,0,0,0,1,1,1,1, -1,-1,-1,-1,0,0,0,0};
    const float cXa[16] = {0,1,-1,0,-1,0,-2,-1, 1,2,0,1,0,1,-1,0};
    float c0 = 0.f, cA = 0.f, cB = 0.f, cX = 0.f;
#pragma unroll
    for (int t = 0; t < 16; ++t) {
        const float p = x[t] * inv;
        c0 += p * c0a[t]; cA += p * cAa[t]; cB += p * cBa[t]; cX += p * cXa[t];
    }
    C4[s] = make_float4(c0, cA, cB, cX);
}

// ---------- prev [K][N] f32 -> prevT [N][K] bf16 (transpose + convert) ------
__global__ __launch_bounds__(256) void transp_conv_kernel(
    const float* __restrict__ src, ushort* __restrict__ dst)
{
    __shared__ ushort tile[64][72];
    const int n0 = blockIdx.x * 64;
    const int k0 = blockIdx.y * 64;
    const int t = threadIdx.x;
#pragma unroll
    for (int it = 0; it < 4; ++it) {
        const int lin = it * 256 + t;      // 0..1023
        const int k = lin >> 4;            // 0..63
        const int n4 = (lin & 15) * 4;     // 0..60
        float4 v = *(const float4*)(src + (size_t)(k0 + k) * N_DIM + n0 + n4);
        tile[n4 + 0][k] = f2bf(v.x);
        tile[n4 + 1][k] = f2bf(v.y);
        tile[n4 + 2][k] = f2bf(v.z);
        tile[n4 + 3][k] = f2bf(v.w);
    }
    __syncthreads();
#pragma unroll
    for (int it = 0; it < 2; ++it) {
        const int lin = it * 256 + t;      // 0..511
        const int n = lin >> 3;            // 0..63
        const int k8 = (lin & 7) * 8;      // 0..56
        int4 v = *(const int4*)&tile[n][k8];
        *(int4*)(dst + (size_t)(n0 + n) * K_DIM + k0 + k8) = v;
    }
}

// ---------------- dual GEMM + gate epilogue ---------------------------------
#define BM 128
#define BN 128
#define BK 64

__global__ __launch_bounds__(256) void logic_gemm_kernel(
    const ushort* __restrict__ Pa,   // [M][K] bf16
    const ushort* __restrict__ Pb,   // [M][K] bf16
    const ushort* __restrict__ Pt,   // prevT [N][K] bf16
    const float4* __restrict__ C4,   // [M]
    float* __restrict__ out)         // [M][N]
{
    __shared__ ushort sA[BM][BK];    // 16 KB, linear (global_load_lds dest)
    __shared__ ushort sB[BM][BK];
    __shared__ ushort sP[BN][BK];

    const int m0 = blockIdx.y * BM;
    const int n0 = blockIdx.x * BN;
    const int t = threadIdx.x;
    const int wid = t >> 6, lane = t & 63;
    const int wr = wid >> 1, wc = wid & 1;   // 2x2 waves, each 64x64 out
    const int lq = lane >> 4;                // quad 0..3
    const int lr = lane & 15;

    // staging geometry: chunk = it*4+wid (1 KB = 8 rows of 64 bf16);
    // lane -> row chunk*8 + (lane>>3), col element (lane&7)*8
    const int g_sub = lane >> 3;
    const int g_col = (lane & 7) * 8;
    const ushort* srcA[4]; const ushort* srcB[4]; const ushort* srcP[4];
    char* dstA[4]; char* dstB[4]; char* dstP[4];
#pragma unroll
    for (int it = 0; it < 4; ++it) {
        const int chunk = it * 4 + wid;
        const int row = chunk * 8 + g_sub;
        srcA[it] = Pa + (size_t)(m0 + row) * K_DIM + g_col;
        srcB[it] = Pb + (size_t)(m0 + row) * K_DIM + g_col;
        srcP[it] = Pt + (size_t)(n0 + row) * K_DIM + g_col;
        dstA[it] = (char*)&sA[0][0] + chunk * 1024;
        dstB[it] = (char*)&sB[0][0] + chunk * 1024;
        dstP[it] = (char*)&sP[0][0] + chunk * 1024;
    }

    f32x4 accA[4][4] = {};
    f32x4 accB[4][4] = {};

    for (int k0 = 0; k0 < K_DIM; k0 += BK) {
        __syncthreads();
#pragma unroll
        for (int it = 0; it < 4; ++it) {
            stage16(srcA[it] + k0, dstA[it]);
            stage16(srcB[it] + k0, dstB[it]);
            stage16(srcP[it] + k0, dstP[it]);
        }
        __syncthreads();   // compiler emits vmcnt(0) drain before barrier
#pragma unroll
        for (int kh = 0; kh < 2; ++kh) {
            const int kbase = kh * 32 + lq * 8;
            s16x8 fa[4], fb[4], fp[4];
#pragma unroll
            for (int i = 0; i < 4; ++i) {
                fa[i] = *(const s16x8*)&sA[wr * 64 + i * 16 + lr][kbase];
                fb[i] = *(const s16x8*)&sB[wr * 64 + i * 16 + lr][kbase];
                fp[i] = *(const s16x8*)&sP[wc * 64 + i * 16 + lr][kbase];
            }
#pragma unroll
            for (int mi = 0; mi < 4; ++mi)
#pragma unroll
                for (int ni = 0; ni < 4; ++ni) {
                    accA[mi][ni] = __builtin_amdgcn_mfma_f32_16x16x32_bf16(
                        fa[mi], fp[ni], accA[mi][ni], 0, 0, 0);
                    accB[mi][ni] = __builtin_amdgcn_mfma_f32_16x16x32_bf16(
                        fb[mi], fp[ni], accB[mi][ni], 0, 0, 0);
                }
        }
    }

    // epilogue: out = c0 + cA*A + cB*B + cAB*A*B
#pragma unroll
    for (int mi = 0; mi < 4; ++mi) {
#pragma unroll
        for (int i = 0; i < 4; ++i) {
            const int row = m0 + wr * 64 + mi * 16 + lq * 4 + i;
            const float4 c = C4[row];
#pragma unroll
            for (int ni = 0; ni < 4; ++ni) {
                const int col = n0 + wc * 64 + ni * 16 + lr;
                const float Av = accA[mi][ni][i];
                const float Bv = accB[mi][ni][i];
                out[(size_t)row * N_DIM + col] = c.x + c.y * Av + c.z * Bv + c.w * Av * Bv;
            }
        }
    }
}

extern "C" void kernel_launch(void* const* d_in, const int* in_sizes, int n_in,
                              void* d_out, int out_size, void* d_ws, size_t ws_size,
                              hipStream_t stream) {
    const float* prev = (const float*)d_in[0];   // [2048][8192]
    const float* Wa   = (const float*)d_in[1];   // [2048][2048]
    const float* Wb   = (const float*)d_in[2];   // [2048][2048]
    const float* TW   = (const float*)d_in[3];   // [16][2048]
    float* out = (float*)d_out;                  // [2048][8192]

    char* ws = (char*)d_ws;
    ushort* Pa = (ushort*)(ws);                          //  8 MiB
    ushort* Pb = (ushort*)(ws + (size_t)(8u << 20));     //  8 MiB
    ushort* Pt = (ushort*)(ws + (size_t)(16u << 20));    // 32 MiB
    float4* C4 = (float4*)(ws + (size_t)(48u << 20));    // 32 KiB

    softmax_rows_kernel<<<dim3(2048, 2), 256, 0, stream>>>(Wa, Wb, Pa, Pb);
    table_c_kernel<<<dim3(8), 256, 0, stream>>>(TW, C4);
    transp_conv_kernel<<<dim3(N_DIM / 64, K_DIM / 64), 256, 0, stream>>>(prev, Pt);
    logic_gemm_kernel<<<dim3(N_DIM / BN, M_DIM / BM), 256, 0, stream>>>(Pa, Pb, Pt, C4, out);
}

// Round 3
// 180.224 us; speedup vs baseline: 1.4640x; 1.4640x over previous
//
#include <hip/hip_runtime.h>
#include <hip/hip_bf16.h>

#define M_DIM 2048   // size
#define K_DIM 2048   // prev_size
#define N_DIM 8192   // batch

#define BM 128
#define BN 256
#define BK 64
#define NT (K_DIM / BK)   // 32 K-tiles

typedef __attribute__((ext_vector_type(4))) float f32x4;
typedef __attribute__((ext_vector_type(8))) short s16x8;

static __device__ __forceinline__ ushort f2bf(float x) {
    __hip_bfloat16 h = __float2bfloat16(x);
    return *reinterpret_cast<ushort*>(&h);
}

// async global->LDS: each lane contributes 16B; LDS dest is wave-uniform base,
// hardware writes base + lane*16 (linear).
static __device__ __forceinline__ void stage1k(const ushort* g, ushort* l) {
    __builtin_amdgcn_global_load_lds(
        (const __attribute__((address_space(1))) void*)g,
        (__attribute__((address_space(3))) void*)l, 16, 0, 0);
}

// ---------------- softmax over rows of Wa/Wb -> bf16 probabilities ----------
__global__ __launch_bounds__(256) void softmax_rows_kernel(
    const float* __restrict__ Wa, const float* __restrict__ Wb,
    ushort* __restrict__ Pa, ushort* __restrict__ Pb)
{
    const float* W = blockIdx.y ? Wb : Wa;
    ushort* P = blockIdx.y ? Pb : Pa;
    const int row = blockIdx.x;
    const int t = threadIdx.x;
    const float* w = W + (size_t)row * K_DIM + t * 8;
    float4 v0 = *(const float4*)(w);
    float4 v1 = *(const float4*)(w + 4);
    float x[8] = {v0.x, v0.y, v0.z, v0.w, v1.x, v1.y, v1.z, v1.w};

    float m = x[0];
#pragma unroll
    for (int i = 1; i < 8; ++i) m = fmaxf(m, x[i]);
#pragma unroll
    for (int off = 32; off >= 1; off >>= 1) m = fmaxf(m, __shfl_xor(m, off));
    __shared__ float redm[4], reds[4];
    const int wid = t >> 6;
    if ((t & 63) == 0) redm[wid] = m;
    __syncthreads();
    m = fmaxf(fmaxf(redm[0], redm[1]), fmaxf(redm[2], redm[3]));

    float s = 0.f;
#pragma unroll
    for (int i = 0; i < 8; ++i) { x[i] = __expf(x[i] - m); s += x[i]; }
#pragma unroll
    for (int off = 32; off >= 1; off >>= 1) s += __shfl_xor(s, off);
    if ((t & 63) == 0) reds[wid] = s;
    __syncthreads();
    s = reds[0] + reds[1] + reds[2] + reds[3];
    const float inv = 1.0f / s;

    union { ushort u[8]; int4 v; } pk;
#pragma unroll
    for (int i = 0; i < 8; ++i) pk.u[i] = f2bf(x[i] * inv);
    *(int4*)(P + (size_t)row * K_DIM + t * 8) = pk.v;
}

// ---------- table softmax (over 16) contracted with gate coeffs -> c[4][M] --
__global__ __launch_bounds__(256) void table_c_kernel(
    const float* __restrict__ TW, float4* __restrict__ C4)
{
    const int s = blockIdx.x * 256 + threadIdx.x;
    if (s >= M_DIM) return;
    float x[16];
    float m = -1e30f;
#pragma unroll
    for (int t = 0; t < 16; ++t) { x[t] = TW[t * M_DIM + s]; m = fmaxf(m, x[t]); }
    float sum = 0.f;
#pragma unroll
    for (int t = 0; t < 16; ++t) { x[t] = __expf(x[t] - m); sum += x[t]; }
    const float inv = 1.0f / sum;

    const float c0a[16] = {0,0,0,0,0,0,0,0, 1,1,1,1,1,1,1,1};
    const float cAa[16] = {0,0,1,1,0,0,1,1, -1,-1,0,0,-1,-1,0,0};
    const float cBa[16] = {0,0,0,0,1,1,1,1, -1,-1,-1,-1,0,0,0,0};
    const float cXa[16] = {0,1,-1,0,-1,0,-2,-1, 1,2,0,1,0,1,-1,0};
    float c0 = 0.f, cA = 0.f, cB = 0.f, cX = 0.f;
#pragma unroll
    for (int t = 0; t < 16; ++t) {
        const float p = x[t] * inv;
        c0 += p * c0a[t]; cA += p * cAa[t]; cB += p * cBa[t]; cX += p * cXa[t];
    }
    C4[s] = make_float4(c0, cA, cB, cX);
}

// ---------- prev [K][N] f32 -> prevT [N][K] bf16 (transpose + convert) ------
__global__ __launch_bounds__(256) void transp_conv_kernel(
    const float* __restrict__ src, ushort* __restrict__ dst)
{
    __shared__ ushort tile[64][72];
    const int n0 = blockIdx.x * 64;
    const int k0 = blockIdx.y * 64;
    const int t = threadIdx.x;
#pragma unroll
    for (int it = 0; it < 4; ++it) {
        const int lin = it * 256 + t;      // 0..1023
        const int k = lin >> 4;            // 0..63
        const int n4 = (lin & 15) * 4;     // 0..60
        float4 v = *(const float4*)(src + (size_t)(k0 + k) * N_DIM + n0 + n4);
        tile[n4 + 0][k] = f2bf(v.x);
        tile[n4 + 1][k] = f2bf(v.y);
        tile[n4 + 2][k] = f2bf(v.z);
        tile[n4 + 3][k] = f2bf(v.w);
    }
    __syncthreads();
#pragma unroll
    for (int it = 0; it < 2; ++it) {
        const int lin = it * 256 + t;      // 0..511
        const int n = lin >> 3;            // 0..63
        const int k8 = (lin & 7) * 8;      // 0..56
        int4 v = *(const int4*)&tile[n][k8];
        *(int4*)(dst + (size_t)(n0 + n) * K_DIM + k0 + k8) = v;
    }
}

// ---------------- dual GEMM, 8-phase schedule + gate epilogue ---------------
// LDS layout: [buf][kh][rows][32] bf16 — each (buf,kh) region is contiguous so
// global_load_lds can stage it; 16B slot p of row r holds logical slot p^(r&3)
// (write side: pre-swizzled global source col; read side: same XOR). 2-way
// residual bank aliasing = free (m136).
//
// Per K-tile, 4 phases: {A*kh0, B*kh0, A*kh1, B*kh1}, 16 MFMA each; prev
// fragments (fp) are register-held across the A/B phase pair (required: S1 of
// tile t+2 overwrites sPt[buf][kh0] during phase 2).
// Stage issue schedule (tile t): ph1 -> S4(t+1); ph2 -> S1(t+2);
// ph3 -> S2(t+2); ph4 -> S3(t+2) then vmcnt(7): drains all of tile t+1
// (8 loads), leaves S1-S3 of t+2 (7 loads) in flight. Never vmcnt(0) except
// at tile NT-2.

#define MFMA16(ACC, FA, FP)                                                    \
    _Pragma("unroll") for (int mi = 0; mi < 4; ++mi)                           \
    _Pragma("unroll") for (int ni = 0; ni < 4; ++ni)                           \
        ACC[mi][ni] = __builtin_amdgcn_mfma_f32_16x16x32_bf16(                 \
            FA[mi], FP[ni], ACC[mi][ni], 0, 0, 0);

#define PHASE_SYNC()                                                           \
    do {                                                                       \
        __builtin_amdgcn_s_barrier();                                          \
        asm volatile("s_waitcnt lgkmcnt(0)" ::: "memory");                     \
        __builtin_amdgcn_sched_barrier(0);                                     \
    } while (0)

#define STAGE_S1(T) do { const int b_ = (T) & 1; const int o_ = (T) * BK;      \
    stage1k(gPa + o_,  &sPa[b_][0][wid * 16][0]);                              \
    stage1k(gPt0 + o_, &sPt[b_][0][wid * 16][0]);                              \
    stage1k(gPt1 + o_, &sPt[b_][0][128 + wid * 16][0]); } while (0)
#define STAGE_S2(T) do { const int b_ = (T) & 1; const int o_ = (T) * BK;      \
    stage1k(gPb + o_,  &sPb[b_][0][wid * 16][0]); } while (0)
#define STAGE_S3(T) do { const int b_ = (T) & 1; const int o_ = (T) * BK + 32; \
    stage1k(gPa + o_,  &sPa[b_][1][wid * 16][0]);                              \
    stage1k(gPt0 + o_, &sPt[b_][1][wid * 16][0]);                              \
    stage1k(gPt1 + o_, &sPt[b_][1][128 + wid * 16][0]); } while (0)
#define STAGE_S4(T) do { const int b_ = (T) & 1; const int o_ = (T) * BK + 32; \
    stage1k(gPb + o_,  &sPb[b_][1][wid * 16][0]); } while (0)

__global__ __launch_bounds__(512, 2) void logic_gemm_kernel(
    const ushort* __restrict__ Pa,   // [M][K] bf16
    const ushort* __restrict__ Pb,   // [M][K] bf16
    const ushort* __restrict__ Pt,   // prevT [N][K] bf16
    const float4* __restrict__ C4,   // [M]
    float* __restrict__ out)         // [M][N]
{
    __shared__ ushort sPa[2][2][128][32];   // 32 KB
    __shared__ ushort sPb[2][2][128][32];   // 32 KB
    __shared__ ushort sPt[2][2][256][32];   // 64 KB

    const int m0 = blockIdx.y * BM;
    const int n0 = blockIdx.x * BN;
    const int t = threadIdx.x;
    const int wid = t >> 6, lane = t & 63;
    const int wr = wid >> 2, wc = wid & 3;   // 2M x 4N waves, 64x64 out each
    const int lq = lane >> 4, lr = lane & 15;

    // staging: lane -> region row (lane>>2), pre-swizzled source col
    const int srow = lane >> 2;                           // 0..15
    const int scol = ((lane & 3) ^ (srow & 3)) << 3;      // elems 0..24
    const ushort* gPa  = Pa + (size_t)(m0 + wid * 16 + srow) * K_DIM + scol;
    const ushort* gPb  = Pb + (size_t)(m0 + wid * 16 + srow) * K_DIM + scol;
    const ushort* gPt0 = Pt + (size_t)(n0 + wid * 16 + srow) * K_DIM + scol;
    const ushort* gPt1 = gPt0 + (size_t)128 * K_DIM;

    // ds_read byte offsets (swizzled): row*64 + (lq*16 ^ ((row&3)*16))
    const int cswz = (lq << 4) ^ ((lr & 3) << 4);
    const int roA = (wr * 64 + lr) * 64 + cswz;   // within [128][32] region
    const int roP = (wc * 64 + lr) * 64 + cswz;   // within [256][32] region

    f32x4 accA[4][4] = {};
    f32x4 accB[4][4] = {};

    // prologue: tile 0 fully + S1-S3 of tile 1 (15 loads); drain to 7.
    STAGE_S1(0); STAGE_S2(0); STAGE_S3(0); STAGE_S4(0);
    STAGE_S1(1); STAGE_S2(1); STAGE_S3(1);
    asm volatile("s_waitcnt vmcnt(7)" ::: "memory");
    __builtin_amdgcn_s_barrier();

    for (int kt = 0; kt < NT; ++kt) {
        const int buf = kt & 1;
        const char* bA0 = (const char*)&sPa[buf][0][0][0];
        const char* bA1 = (const char*)&sPa[buf][1][0][0];
        const char* bB0 = (const char*)&sPb[buf][0][0][0];
        const char* bB1 = (const char*)&sPb[buf][1][0][0];
        const char* bP0 = (const char*)&sPt[buf][0][0][0];
        const char* bP1 = (const char*)&sPt[buf][1][0][0];
        s16x8 fa[4], fp[4];

        // ---- phase 1: A x kh0 (reads sPa[buf][0], sPt[buf][0]) ----
#pragma unroll
        for (int i = 0; i < 4; ++i) fa[i] = *(const s16x8*)(bA0 + roA + i * 1024);
#pragma unroll
        for (int i = 0; i < 4; ++i) fp[i] = *(const s16x8*)(bP0 + roP + i * 1024);
        if (kt + 1 < NT) STAGE_S4(kt + 1);
        PHASE_SYNC();
        __builtin_amdgcn_s_setprio(1);
        MFMA16(accA, fa, fp);
        __builtin_amdgcn_s_setprio(0);
        __builtin_amdgcn_s_barrier();

        // ---- phase 2: B x kh0 (reads sPb[buf][0]; fp reg-held) ----
#pragma unroll
        for (int i = 0; i < 4; ++i) fa[i] = *(const s16x8*)(bB0 + roA + i * 1024);
        if (kt + 2 < NT) STAGE_S1(kt + 2);
        PHASE_SYNC();
        __builtin_amdgcn_s_setprio(1);
        MFMA16(accB, fa, fp);
        __builtin_amdgcn_s_setprio(0);
        __builtin_amdgcn_s_barrier();

        // ---- phase 3: A x kh1 (reads sPa[buf][1], sPt[buf][1]) ----
#pragma unroll
        for (int i = 0; i < 4; ++i) fa[i] = *(const s16x8*)(bA1 + roA + i * 1024);
#pragma unroll
        for (int i = 0; i < 4; ++i) fp[i] = *(const s16x8*)(bP1 + roP + i * 1024);
        if (kt + 2 < NT) STAGE_S2(kt + 2);
        PHASE_SYNC();
        __builtin_amdgcn_s_setprio(1);
        MFMA16(accA, fa, fp);
        __builtin_amdgcn_s_setprio(0);
        __builtin_amdgcn_s_barrier();

        // ---- phase 4: B x kh1 (reads sPb[buf][1]; fp reg-held) ----
#pragma unroll
        for (int i = 0; i < 4; ++i) fa[i] = *(const s16x8*)(bB1 + roA + i * 1024);
        if (kt + 2 < NT) STAGE_S3(kt + 2);
        if (kt < NT - 2)       asm volatile("s_waitcnt vmcnt(7)" ::: "memory");
        else if (kt == NT - 2) asm volatile("s_waitcnt vmcnt(0)" ::: "memory");
        PHASE_SYNC();
        __builtin_amdgcn_s_setprio(1);
        MFMA16(accB, fa, fp);
        __builtin_amdgcn_s_setprio(0);
        __builtin_amdgcn_s_barrier();
    }

    // epilogue: out = c0 + cA*A + cB*B + cAB*A*B
#pragma unroll
    for (int mi = 0; mi < 4; ++mi) {
#pragma unroll
        for (int i = 0; i < 4; ++i) {
            const int row = m0 + wr * 64 + mi * 16 + lq * 4 + i;
            const float4 c = C4[row];
#pragma unroll
            for (int ni = 0; ni < 4; ++ni) {
                const int col = n0 + wc * 64 + ni * 16 + lr;
                const float Av = accA[mi][ni][i];
                const float Bv = accB[mi][ni][i];
                out[(size_t)row * N_DIM + col] = c.x + c.y * Av + c.z * Bv + c.w * Av * Bv;
            }
        }
    }
}

extern "C" void kernel_launch(void* const* d_in, const int* in_sizes, int n_in,
                              void* d_out, int out_size, void* d_ws, size_t ws_size,
                              hipStream_t stream) {
    const float* prev = (const float*)d_in[0];   // [2048][8192]
    const float* Wa   = (const float*)d_in[1];   // [2048][2048]
    const float* Wb   = (const float*)d_in[2];   // [2048][2048]
    const float* TW   = (const float*)d_in[3];   // [16][2048]
    float* out = (float*)d_out;                  // [2048][8192]

    char* ws = (char*)d_ws;
    ushort* Pa = (ushort*)(ws);                          //  8 MiB
    ushort* Pb = (ushort*)(ws + (size_t)(8u << 20));     //  8 MiB
    ushort* Pt = (ushort*)(ws + (size_t)(16u << 20));    // 32 MiB
    float4* C4 = (float4*)(ws + (size_t)(48u << 20));    // 32 KiB

    softmax_rows_kernel<<<dim3(2048, 2), 256, 0, stream>>>(Wa, Wb, Pa, Pb);
    table_c_kernel<<<dim3(8), 256, 0, stream>>>(TW, C4);
    transp_conv_kernel<<<dim3(N_DIM / 64, K_DIM / 64), 256, 0, stream>>>(prev, Pt);
    logic_gemm_kernel<<<dim3(N_DIM / BN, M_DIM / BM), 512, 0, stream>>>(Pa, Pb, Pt, C4, out);
}

// Round 4
// 168.836 us; speedup vs baseline: 1.5628x; 1.0675x over previous
//
#include <hip/hip_runtime.h>
#include <hip/hip_bf16.h>

#define M_DIM 2048   // size
#define K_DIM 2048   // prev_size
#define N_DIM 8192   // batch

#define BM 128
#define BN 256
#define BK 64
#define NT (K_DIM / BK)   // 32 K-tiles

typedef __attribute__((ext_vector_type(4))) float f32x4;
typedef __attribute__((ext_vector_type(8))) short s16x8;

static __device__ __forceinline__ ushort f2bf(float x) {
    __hip_bfloat16 h = __float2bfloat16(x);
    return *reinterpret_cast<ushort*>(&h);
}

// async global->LDS: each lane contributes 16B; LDS dest is wave-uniform base,
// hardware writes base + lane*16 (linear).
static __device__ __forceinline__ void stage1k(const ushort* g, ushort* l) {
    __builtin_amdgcn_global_load_lds(
        (const __attribute__((address_space(1))) void*)g,
        (__attribute__((address_space(3))) void*)l, 16, 0, 0);
}

// ---------------- softmax over rows of Wa/Wb -> bf16 probabilities ----------
__global__ __launch_bounds__(256) void softmax_rows_kernel(
    const float* __restrict__ Wa, const float* __restrict__ Wb,
    ushort* __restrict__ Pa, ushort* __restrict__ Pb)
{
    const float* W = blockIdx.y ? Wb : Wa;
    ushort* P = blockIdx.y ? Pb : Pa;
    const int row = blockIdx.x;
    const int t = threadIdx.x;
    const float* w = W + (size_t)row * K_DIM + t * 8;
    float4 v0 = *(const float4*)(w);
    float4 v1 = *(const float4*)(w + 4);
    float x[8] = {v0.x, v0.y, v0.z, v0.w, v1.x, v1.y, v1.z, v1.w};

    float m = x[0];
#pragma unroll
    for (int i = 1; i < 8; ++i) m = fmaxf(m, x[i]);
#pragma unroll
    for (int off = 32; off >= 1; off >>= 1) m = fmaxf(m, __shfl_xor(m, off));
    __shared__ float redm[4], reds[4];
    const int wid = t >> 6;
    if ((t & 63) == 0) redm[wid] = m;
    __syncthreads();
    m = fmaxf(fmaxf(redm[0], redm[1]), fmaxf(redm[2], redm[3]));

    float s = 0.f;
#pragma unroll
    for (int i = 0; i < 8; ++i) { x[i] = __expf(x[i] - m); s += x[i]; }
#pragma unroll
    for (int off = 32; off >= 1; off >>= 1) s += __shfl_xor(s, off);
    if ((t & 63) == 0) reds[wid] = s;
    __syncthreads();
    s = reds[0] + reds[1] + reds[2] + reds[3];
    const float inv = 1.0f / s;

    union { ushort u[8]; int4 v; } pk;
#pragma unroll
    for (int i = 0; i < 8; ++i) pk.u[i] = f2bf(x[i] * inv);
    *(int4*)(P + (size_t)row * K_DIM + t * 8) = pk.v;
}

// ---------- table softmax (over 16) contracted with gate coeffs -> c[4][M] --
__global__ __launch_bounds__(256) void table_c_kernel(
    const float* __restrict__ TW, float4* __restrict__ C4)
{
    const int s = blockIdx.x * 256 + threadIdx.x;
    if (s >= M_DIM) return;
    float x[16];
    float m = -1e30f;
#pragma unroll
    for (int t = 0; t < 16; ++t) { x[t] = TW[t * M_DIM + s]; m = fmaxf(m, x[t]); }
    float sum = 0.f;
#pragma unroll
    for (int t = 0; t < 16; ++t) { x[t] = __expf(x[t] - m); sum += x[t]; }
    const float inv = 1.0f / sum;

    const float c0a[16] = {0,0,0,0,0,0,0,0, 1,1,1,1,1,1,1,1};
    const float cAa[16] = {0,0,1,1,0,0,1,1, -1,-1,0,0,-1,-1,0,0};
    const float cBa[16] = {0,0,0,0,1,1,1,1, -1,-1,-1,-1,0,0,0,0};
    const float cXa[16] = {0,1,-1,0,-1,0,-2,-1, 1,2,0,1,0,1,-1,0};
    float c0 = 0.f, cA = 0.f, cB = 0.f, cX = 0.f;
#pragma unroll
    for (int t = 0; t < 16; ++t) {
        const float p = x[t] * inv;
        c0 += p * c0a[t]; cA += p * cAa[t]; cB += p * cBa[t]; cX += p * cXa[t];
    }
    C4[s] = make_float4(c0, cA, cB, cX);
}

// ---------- prev [K][N] f32 -> prevT [N][K] bf16 (transpose + convert) ------
__global__ __launch_bounds__(256) void transp_conv_kernel(
    const float* __restrict__ src, ushort* __restrict__ dst)
{
    __shared__ ushort tile[64][72];
    const int n0 = blockIdx.x * 64;
    const int k0 = blockIdx.y * 64;
    const int t = threadIdx.x;
#pragma unroll
    for (int it = 0; it < 4; ++it) {
        const int lin = it * 256 + t;      // 0..1023
        const int k = lin >> 4;            // 0..63
        const int n4 = (lin & 15) * 4;     // 0..60
        float4 v = *(const float4*)(src + (size_t)(k0 + k) * N_DIM + n0 + n4);
        tile[n4 + 0][k] = f2bf(v.x);
        tile[n4 + 1][k] = f2bf(v.y);
        tile[n4 + 2][k] = f2bf(v.z);
        tile[n4 + 3][k] = f2bf(v.w);
    }
    __syncthreads();
#pragma unroll
    for (int it = 0; it < 2; ++it) {
        const int lin = it * 256 + t;      // 0..511
        const int n = lin >> 3;            // 0..63
        const int k8 = (lin & 7) * 8;      // 0..56
        int4 v = *(const int4*)&tile[n][k8];
        *(int4*)(dst + (size_t)(n0 + n) * K_DIM + k0 + k8) = v;
    }
}

// ---------------- dual GEMM, 8-phase schedule + gate epilogue ---------------
// LDS layout: [buf][kh][rows][32] bf16, contiguous per (buf,kh) region so
// global_load_lds can stage it linearly. Swizzle: 16B slot p of row r holds
// logical slot p ^ sigma(r), sigma(r) = (r>>1)&3. Bank group of (r, slot s)
// = 16*(r&1) + 4*s; sigma makes (r&1, sigma(r)) distinct over r mod 8, so a
// 16-lane quarter-wave reading rows 0..15 at one logical slot covers all 8
// bank groups twice = free 2-way (m136). (Round-3's sigma=r&3 only hit 4
// groups -> 4-way, conflicts stayed 1.26e7.)
//
// Per K-tile, 4 phases: {A*kh0, B*kh0, A*kh1, B*kh1}, 16 MFMA each; prev
// fragments (fp) are register-held across the A/B phase pair (required: S1 of
// tile t+2 overwrites sPt[buf][kh0] during phase 2).
// Stage issue schedule (tile t): ph1 -> S4(t+1); ph2 -> S1(t+2);
// ph3 -> S2(t+2); ph4 -> S3(t+2) then vmcnt(7): drains all of tile t+1
// (8 loads), leaves S1-S3 of t+2 (7 loads) in flight. Never vmcnt(0) except
// at tile NT-2.

#define MFMA16(ACC, FA, FP)                                                    \
    _Pragma("unroll") for (int mi = 0; mi < 4; ++mi)                           \
    _Pragma("unroll") for (int ni = 0; ni < 4; ++ni)                           \
        ACC[mi][ni] = __builtin_amdgcn_mfma_f32_16x16x32_bf16(                 \
            FA[mi], FP[ni], ACC[mi][ni], 0, 0, 0);

#define PHASE_SYNC()                                                           \
    do {                                                                       \
        __builtin_amdgcn_s_barrier();                                          \
        asm volatile("s_waitcnt lgkmcnt(0)" ::: "memory");                     \
        __builtin_amdgcn_sched_barrier(0);                                     \
    } while (0)

#define STAGE_S1(T) do { const int b_ = (T) & 1; const int o_ = (T) * BK;      \
    stage1k(gPa + o_,  &sPa[b_][0][wid * 16][0]);                              \
    stage1k(gPt0 + o_, &sPt[b_][0][wid * 16][0]);                              \
    stage1k(gPt1 + o_, &sPt[b_][0][128 + wid * 16][0]); } while (0)
#define STAGE_S2(T) do { const int b_ = (T) & 1; const int o_ = (T) * BK;      \
    stage1k(gPb + o_,  &sPb[b_][0][wid * 16][0]); } while (0)
#define STAGE_S3(T) do { const int b_ = (T) & 1; const int o_ = (T) * BK + 32; \
    stage1k(gPa + o_,  &sPa[b_][1][wid * 16][0]);                              \
    stage1k(gPt0 + o_, &sPt[b_][1][wid * 16][0]);                              \
    stage1k(gPt1 + o_, &sPt[b_][1][128 + wid * 16][0]); } while (0)
#define STAGE_S4(T) do { const int b_ = (T) & 1; const int o_ = (T) * BK + 32; \
    stage1k(gPb + o_,  &sPb[b_][1][wid * 16][0]); } while (0)

__global__ __launch_bounds__(512, 2) void logic_gemm_kernel(
    const ushort* __restrict__ Pa,   // [M][K] bf16
    const ushort* __restrict__ Pb,   // [M][K] bf16
    const ushort* __restrict__ Pt,   // prevT [N][K] bf16
    const float4* __restrict__ C4,   // [M]
    float* __restrict__ out)         // [M][N]
{
    __shared__ ushort sPa[2][2][128][32];   // 32 KB
    __shared__ ushort sPb[2][2][128][32];   // 32 KB
    __shared__ ushort sPt[2][2][256][32];   // 64 KB

    const int m0 = blockIdx.y * BM;
    const int n0 = blockIdx.x * BN;
    const int t = threadIdx.x;
    const int wid = t >> 6, lane = t & 63;
    const int wr = wid >> 2, wc = wid & 3;   // 2M x 4N waves, 64x64 out each
    const int lq = lane >> 4, lr = lane & 15;

    // staging: lane -> region row (lane>>2), pre-swizzled source col
    // sigma(srow) = (srow>>1)&3 = (lane>>3)&3
    const int srow = lane >> 2;                               // 0..15
    const int scol = (((lane & 3) ^ ((lane >> 3) & 3)) << 3); // elems {0,8,16,24}
    const ushort* gPa  = Pa + (size_t)(m0 + wid * 16 + srow) * K_DIM + scol;
    const ushort* gPb  = Pb + (size_t)(m0 + wid * 16 + srow) * K_DIM + scol;
    const ushort* gPt0 = Pt + (size_t)(n0 + wid * 16 + srow) * K_DIM + scol;
    const ushort* gPt1 = gPt0 + (size_t)128 * K_DIM;

    // ds_read byte offsets (swizzled): row*64 + 16*(lq ^ sigma(row)); within a
    // 16-row block sigma(row) = (lr>>1)&3 (block offsets are multiples of 16).
    const int cswz = (lq ^ ((lr >> 1) & 3)) << 4;
    const int roA = (wr * 64 + lr) * 64 + cswz;   // within [128][32] region
    const int roP = (wc * 64 + lr) * 64 + cswz;   // within [256][32] region

    f32x4 accA[4][4] = {};
    f32x4 accB[4][4] = {};

    // prologue: tile 0 fully + S1-S3 of tile 1 (15 loads); drain to 7.
    STAGE_S1(0); STAGE_S2(0); STAGE_S3(0); STAGE_S4(0);
    STAGE_S1(1); STAGE_S2(1); STAGE_S3(1);
    asm volatile("s_waitcnt vmcnt(7)" ::: "memory");
    __builtin_amdgcn_s_barrier();

    for (int kt = 0; kt < NT; ++kt) {
        const int buf = kt & 1;
        const char* bA0 = (const char*)&sPa[buf][0][0][0];
        const char* bA1 = (const char*)&sPa[buf][1][0][0];
        const char* bB0 = (const char*)&sPb[buf][0][0][0];
        const char* bB1 = (const char*)&sPb[buf][1][0][0];
        const char* bP0 = (const char*)&sPt[buf][0][0][0];
        const char* bP1 = (const char*)&sPt[buf][1][0][0];
        s16x8 fa[4], fp[4];

        // ---- phase 1: A x kh0 (reads sPa[buf][0], sPt[buf][0]) ----
#pragma unroll
        for (int i = 0; i < 4; ++i) fa[i] = *(const s16x8*)(bA0 + roA + i * 1024);
#pragma unroll
        for (int i = 0; i < 4; ++i) fp[i] = *(const s16x8*)(bP0 + roP + i * 1024);
        if (kt + 1 < NT) STAGE_S4(kt + 1);
        PHASE_SYNC();
        __builtin_amdgcn_s_setprio(1);
        MFMA16(accA, fa, fp);
        __builtin_amdgcn_s_setprio(0);
        __builtin_amdgcn_s_barrier();

        // ---- phase 2: B x kh0 (reads sPb[buf][0]; fp reg-held) ----
#pragma unroll
        for (int i = 0; i < 4; ++i) fa[i] = *(const s16x8*)(bB0 + roA + i * 1024);
        if (kt + 2 < NT) STAGE_S1(kt + 2);
        PHASE_SYNC();
        __builtin_amdgcn_s_setprio(1);
        MFMA16(accB, fa, fp);
        __builtin_amdgcn_s_setprio(0);
        __builtin_amdgcn_s_barrier();

        // ---- phase 3: A x kh1 (reads sPa[buf][1], sPt[buf][1]) ----
#pragma unroll
        for (int i = 0; i < 4; ++i) fa[i] = *(const s16x8*)(bA1 + roA + i * 1024);
#pragma unroll
        for (int i = 0; i < 4; ++i) fp[i] = *(const s16x8*)(bP1 + roP + i * 1024);
        if (kt + 2 < NT) STAGE_S2(kt + 2);
        PHASE_SYNC();
        __builtin_amdgcn_s_setprio(1);
        MFMA16(accA, fa, fp);
        __builtin_amdgcn_s_setprio(0);
        __builtin_amdgcn_s_barrier();

        // ---- phase 4: B x kh1 (reads sPb[buf][1]; fp reg-held) ----
#pragma unroll
        for (int i = 0; i < 4; ++i) fa[i] = *(const s16x8*)(bB1 + roA + i * 1024);
        if (kt + 2 < NT) STAGE_S3(kt + 2);
        if (kt < NT - 2)       asm volatile("s_waitcnt vmcnt(7)" ::: "memory");
        else if (kt == NT - 2) asm volatile("s_waitcnt vmcnt(0)" ::: "memory");
        PHASE_SYNC();
        __builtin_amdgcn_s_setprio(1);
        MFMA16(accB, fa, fp);
        __builtin_amdgcn_s_setprio(0);
        __builtin_amdgcn_s_barrier();
    }

    // epilogue: out = c0 + cA*A + cB*B + cAB*A*B
#pragma unroll
    for (int mi = 0; mi < 4; ++mi) {
#pragma unroll
        for (int i = 0; i < 4; ++i) {
            const int row = m0 + wr * 64 + mi * 16 + lq * 4 + i;
            const float4 c = C4[row];
#pragma unroll
            for (int ni = 0; ni < 4; ++ni) {
                const int col = n0 + wc * 64 + ni * 16 + lr;
                const float Av = accA[mi][ni][i];
                const float Bv = accB[mi][ni][i];
                out[(size_t)row * N_DIM + col] = c.x + c.y * Av + c.z * Bv + c.w * Av * Bv;
            }
        }
    }
}

extern "C" void kernel_launch(void* const* d_in, const int* in_sizes, int n_in,
                              void* d_out, int out_size, void* d_ws, size_t ws_size,
                              hipStream_t stream) {
    const float* prev = (const float*)d_in[0];   // [2048][8192]
    const float* Wa   = (const float*)d_in[1];   // [2048][2048]
    const float* Wb   = (const float*)d_in[2];   // [2048][2048]
    const float* TW   = (const float*)d_in[3];   // [16][2048]
    float* out = (float*)d_out;                  // [2048][8192]

    char* ws = (char*)d_ws;
    ushort* Pa = (ushort*)(ws);                          //  8 MiB
    ushort* Pb = (ushort*)(ws + (size_t)(8u << 20));     //  8 MiB
    ushort* Pt = (ushort*)(ws + (size_t)(16u << 20));    // 32 MiB
    float4* C4 = (float4*)(ws + (size_t)(48u << 20));    // 32 KiB

    softmax_rows_kernel<<<dim3(2048, 2), 256, 0, stream>>>(Wa, Wb, Pa, Pb);
    table_c_kernel<<<dim3(8), 256, 0, stream>>>(TW, C4);
    transp_conv_kernel<<<dim3(N_DIM / 64, K_DIM / 64), 256, 0, stream>>>(prev, Pt);
    logic_gemm_kernel<<<dim3(N_DIM / BN, M_DIM / BM), 512, 0, stream>>>(Pa, Pb, Pt, C4, out);
}

// Round 5
// 145.334 us; speedup vs baseline: 1.8155x; 1.1617x over previous
//
#include <hip/hip_runtime.h>
#include <hip/hip_bf16.h>

#define M_DIM 2048   // size
#define K_DIM 2048   // prev_size
#define N_DIM 8192   // batch

#define BM 128
#define BN 256
#define BK 64
#define NT (K_DIM / BK)   // 32 K-tiles

typedef __attribute__((ext_vector_type(4))) float f32x4;
typedef __attribute__((ext_vector_type(8))) short s16x8;

static __device__ __forceinline__ ushort f2bf(float x) {
    __hip_bfloat16 h = __float2bfloat16(x);
    return *reinterpret_cast<ushort*>(&h);
}

// async global->LDS: each lane contributes 16B; LDS dest is wave-uniform base,
// hardware writes base + lane*16 (linear).
static __device__ __forceinline__ void stage1k(const ushort* g, ushort* l) {
    __builtin_amdgcn_global_load_lds(
        (const __attribute__((address_space(1))) void*)g,
        (__attribute__((address_space(3))) void*)l, 16, 0, 0);
}

// ---------------- softmax over rows of Wa/Wb -> bf16 probabilities ----------
__global__ __launch_bounds__(256) void softmax_rows_kernel(
    const float* __restrict__ Wa, const float* __restrict__ Wb,
    ushort* __restrict__ Pa, ushort* __restrict__ Pb)
{
    const float* W = blockIdx.y ? Wb : Wa;
    ushort* P = blockIdx.y ? Pb : Pa;
    const int row = blockIdx.x;
    const int t = threadIdx.x;
    const float* w = W + (size_t)row * K_DIM + t * 8;
    float4 v0 = *(const float4*)(w);
    float4 v1 = *(const float4*)(w + 4);
    float x[8] = {v0.x, v0.y, v0.z, v0.w, v1.x, v1.y, v1.z, v1.w};

    float m = x[0];
#pragma unroll
    for (int i = 1; i < 8; ++i) m = fmaxf(m, x[i]);
#pragma unroll
    for (int off = 32; off >= 1; off >>= 1) m = fmaxf(m, __shfl_xor(m, off));
    __shared__ float redm[4], reds[4];
    const int wid = t >> 6;
    if ((t & 63) == 0) redm[wid] = m;
    __syncthreads();
    m = fmaxf(fmaxf(redm[0], redm[1]), fmaxf(redm[2], redm[3]));

    float s = 0.f;
#pragma unroll
    for (int i = 0; i < 8; ++i) { x[i] = __expf(x[i] - m); s += x[i]; }
#pragma unroll
    for (int off = 32; off >= 1; off >>= 1) s += __shfl_xor(s, off);
    if ((t & 63) == 0) reds[wid] = s;
    __syncthreads();
    s = reds[0] + reds[1] + reds[2] + reds[3];
    const float inv = 1.0f / s;

    union { ushort u[8]; int4 v; } pk;
#pragma unroll
    for (int i = 0; i < 8; ++i) pk.u[i] = f2bf(x[i] * inv);
    *(int4*)(P + (size_t)row * K_DIM + t * 8) = pk.v;
}

// ---------- table softmax (over 16) contracted with gate coeffs -> c[4][M] --
__global__ __launch_bounds__(256) void table_c_kernel(
    const float* __restrict__ TW, float4* __restrict__ C4)
{
    const int s = blockIdx.x * 256 + threadIdx.x;
    if (s >= M_DIM) return;
    float x[16];
    float m = -1e30f;
#pragma unroll
    for (int t = 0; t < 16; ++t) { x[t] = TW[t * M_DIM + s]; m = fmaxf(m, x[t]); }
    float sum = 0.f;
#pragma unroll
    for (int t = 0; t < 16; ++t) { x[t] = __expf(x[t] - m); sum += x[t]; }
    const float inv = 1.0f / sum;

    const float c0a[16] = {0,0,0,0,0,0,0,0, 1,1,1,1,1,1,1,1};
    const float cAa[16] = {0,0,1,1,0,0,1,1, -1,-1,0,0,-1,-1,0,0};
    const float cBa[16] = {0,0,0,0,1,1,1,1, -1,-1,-1,-1,0,0,0,0};
    const float cXa[16] = {0,1,-1,0,-1,0,-2,-1, 1,2,0,1,0,1,-1,0};
    float c0 = 0.f, cA = 0.f, cB = 0.f, cX = 0.f;
#pragma unroll
    for (int t = 0; t < 16; ++t) {
        const float p = x[t] * inv;
        c0 += p * c0a[t]; cA += p * cAa[t]; cB += p * cBa[t]; cX += p * cXa[t];
    }
    C4[s] = make_float4(c0, cA, cB, cX);
}

// ---------- prev [K][N] f32 -> prevT [N][K] bf16 (transpose + convert) ------
__global__ __launch_bounds__(256) void transp_conv_kernel(
    const float* __restrict__ src, ushort* __restrict__ dst)
{
    __shared__ ushort tile[64][72];
    const int n0 = blockIdx.x * 64;
    const int k0 = blockIdx.y * 64;
    const int t = threadIdx.x;
#pragma unroll
    for (int it = 0; it < 4; ++it) {
        const int lin = it * 256 + t;      // 0..1023
        const int k = lin >> 4;            // 0..63
        const int n4 = (lin & 15) * 4;     // 0..60
        float4 v = *(const float4*)(src + (size_t)(k0 + k) * N_DIM + n0 + n4);
        tile[n4 + 0][k] = f2bf(v.x);
        tile[n4 + 1][k] = f2bf(v.y);
        tile[n4 + 2][k] = f2bf(v.z);
        tile[n4 + 3][k] = f2bf(v.w);
    }
    __syncthreads();
#pragma unroll
    for (int it = 0; it < 2; ++it) {
        const int lin = it * 256 + t;      // 0..511
        const int n = lin >> 3;            // 0..63
        const int k8 = (lin & 7) * 8;      // 0..56
        int4 v = *(const int4*)&tile[n][k8];
        *(int4*)(dst + (size_t)(n0 + n) * K_DIM + k0 + k8) = v;
    }
}

// ------------- dual GEMM, pipelined 4-phase schedule + gate epilogue --------
// LDS: [buf][kh][rows][32] bf16 per operand; swizzle sigma(r) = (r>>1)&3 on
// 16B slots (write: pre-swizzled global col; read: same XOR) -> conflict-free
// (verified: SQ_LDS_BANK_CONFLICT = 0 in R4).
//
// Phase p (one barrier each): lgkmcnt(0) [frags read in p-1 now ready];
// 8 MFMA; [vmcnt guard]; issue ds_reads for p+1 + 2 stage loads; 8 MFMA;
// barrier. ds_reads/stages execute on LDS/VMEM pipes UNDER the MFMA cluster.
//
// Stage pairs (2 loads each) for tile T, issued 5-8 phases ahead:
//   A(T)@ph2(T-2): Pa kh0 -> sPa[b][0],      Pt0 kh0 -> sPt[b][0] rows 0-127
//   B(T)@ph3(T-2): Pt1 kh0 -> sPt[b][0] 128+, Pb kh0 -> sPb[b][0]
//   C(T)@ph4(T-2): Pa kh1 -> sPa[b][1],      Pt0 kh1 -> sPt[b][1] rows 0-127
//   D(T)@ph1(T-1): Pt1 kh1 -> sPt[b][1] 128+, Pb kh1 -> sPb[b][1]
// vmcnt ledger (loads, steady state): guard@ph1 = 6 (drains D(t); needed by
// ph2/ph3 reads, 1+ barrier later); guard@ph3 = 6 (drains A,B(t+1); needed by
// ph4 reads). Each region's writes issue >= 2 phases after its last read,
// whose lgkm-drain at the next phase head precedes the intervening barrier ->
// race-free with one barrier/phase. Tail (kt >= NT-2): vmcnt(0).

#define MFMA8(ACC, FA, FP, MI0)                                                \
    _Pragma("unroll") for (int mi = (MI0); mi < (MI0) + 2; ++mi)               \
    _Pragma("unroll") for (int ni = 0; ni < 4; ++ni)                           \
        ACC[mi][ni] = __builtin_amdgcn_mfma_f32_16x16x32_bf16(                 \
            FA[mi], FP[ni], ACC[mi][ni], 0, 0, 0);

#define LGKM0_FENCE()                                                          \
    do {                                                                       \
        asm volatile("s_waitcnt lgkmcnt(0)" ::: "memory");                     \
        __builtin_amdgcn_sched_barrier(0);                                     \
    } while (0)

#define STAGE_A(T) do { const int b_ = (T) & 1; const int o_ = (T) * BK;       \
    stage1k(gPa + o_,  &sPa[b_][0][wid * 16][0]);                              \
    stage1k(gPt0 + o_, &sPt[b_][0][wid * 16][0]); } while (0)
#define STAGE_B(T) do { const int b_ = (T) & 1; const int o_ = (T) * BK;       \
    stage1k(gPt1 + o_, &sPt[b_][0][128 + wid * 16][0]);                        \
    stage1k(gPb + o_,  &sPb[b_][0][wid * 16][0]); } while (0)
#define STAGE_C(T) do { const int b_ = (T) & 1; const int o_ = (T) * BK + 32;  \
    stage1k(gPa + o_,  &sPa[b_][1][wid * 16][0]);                              \
    stage1k(gPt0 + o_, &sPt[b_][1][wid * 16][0]); } while (0)
#define STAGE_D(T) do { const int b_ = (T) & 1; const int o_ = (T) * BK + 32;  \
    stage1k(gPt1 + o_, &sPt[b_][1][128 + wid * 16][0]);                        \
    stage1k(gPb + o_,  &sPb[b_][1][wid * 16][0]); } while (0)

__global__ __launch_bounds__(512, 2) void logic_gemm_kernel(
    const ushort* __restrict__ Pa,   // [M][K] bf16
    const ushort* __restrict__ Pb,   // [M][K] bf16
    const ushort* __restrict__ Pt,   // prevT [N][K] bf16
    const float4* __restrict__ C4,   // [M]
    float* __restrict__ out)         // [M][N]
{
    __shared__ ushort sPa[2][2][128][32];   // 32 KB
    __shared__ ushort sPb[2][2][128][32];   // 32 KB
    __shared__ ushort sPt[2][2][256][32];   // 64 KB

    const int m0 = blockIdx.y * BM;
    const int n0 = blockIdx.x * BN;
    const int t = threadIdx.x;
    const int wid = t >> 6, lane = t & 63;
    const int wr = wid >> 2, wc = wid & 3;   // 2M x 4N waves, 64x64 out each
    const int lq = lane >> 4, lr = lane & 15;

    // staging: lane -> region row (lane>>2), pre-swizzled source col
    const int srow = lane >> 2;                               // 0..15
    const int scol = (((lane & 3) ^ ((lane >> 3) & 3)) << 3); // {0,8,16,24}
    const ushort* gPa  = Pa + (size_t)(m0 + wid * 16 + srow) * K_DIM + scol;
    const ushort* gPb  = Pb + (size_t)(m0 + wid * 16 + srow) * K_DIM + scol;
    const ushort* gPt0 = Pt + (size_t)(n0 + wid * 16 + srow) * K_DIM + scol;
    const ushort* gPt1 = gPt0 + (size_t)128 * K_DIM;

    // ds_read byte offsets (swizzled): row*64 + 16*(lq ^ sigma(row))
    const int cswz = (lq ^ ((lr >> 1) & 3)) << 4;
    const int roA = (wr * 64 + lr) * 64 + cswz;   // within [128][32] region
    const int roP = (wc * 64 + lr) * 64 + cswz;   // within [256][32] region

    f32x4 accA[4][4] = {};
    f32x4 accB[4][4] = {};
    s16x8 fX0[4], fX1[4], fpA[4], fpB[4];

    // prologue: A,B,C,D(0), A,B,C(1) = 14 loads; drain first 4 (A,B(0));
    // barrier; pre-read tile-0 kh0 fragments.
    STAGE_A(0); STAGE_B(0); STAGE_C(0); STAGE_D(0);
    STAGE_A(1); STAGE_B(1); STAGE_C(1);
    asm volatile("s_waitcnt vmcnt(10)" ::: "memory");
    __builtin_amdgcn_s_barrier();
#pragma unroll
    for (int i = 0; i < 4; ++i)
        fX0[i] = *(const s16x8*)((const char*)&sPa[0][0][0][0] + roA + i * 1024);
#pragma unroll
    for (int i = 0; i < 4; ++i)
        fpA[i] = *(const s16x8*)((const char*)&sPt[0][0][0][0] + roP + i * 1024);

    for (int kt = 0; kt < NT; ++kt) {
        const int buf = kt & 1;
        const char* bA1 = (const char*)&sPa[buf][1][0][0];
        const char* bB0 = (const char*)&sPb[buf][0][0][0];
        const char* bB1 = (const char*)&sPb[buf][1][0][0];
        const char* bP1 = (const char*)&sPt[buf][1][0][0];
        const char* nA0 = (const char*)&sPa[buf ^ 1][0][0][0];
        const char* nP0 = (const char*)&sPt[buf ^ 1][0][0][0];

        // -------- phase 1: accA x kh0 (uses fX0, fpA) --------
        LGKM0_FENCE();
        __builtin_amdgcn_s_setprio(1);
        MFMA8(accA, fX0, fpA, 0);
        __builtin_amdgcn_s_setprio(0);
        __builtin_amdgcn_sched_barrier(0);
        if (kt < NT - 2) asm volatile("s_waitcnt vmcnt(6)" ::: "memory");
        else             asm volatile("s_waitcnt vmcnt(0)" ::: "memory");
#pragma unroll
        for (int i = 0; i < 4; ++i) fX1[i] = *(const s16x8*)(bB0 + roA + i * 1024);
        if (kt + 1 < NT) STAGE_D(kt + 1);
        __builtin_amdgcn_sched_barrier(0);
        __builtin_amdgcn_s_setprio(1);
        MFMA8(accA, fX0, fpA, 2);
        __builtin_amdgcn_s_setprio(0);
        __builtin_amdgcn_s_barrier();

        // -------- phase 2: accB x kh0 (uses fX1, fpA) --------
        LGKM0_FENCE();
        __builtin_amdgcn_s_setprio(1);
        MFMA8(accB, fX1, fpA, 0);
        __builtin_amdgcn_s_setprio(0);
        __builtin_amdgcn_sched_barrier(0);
#pragma unroll
        for (int i = 0; i < 4; ++i) fX0[i] = *(const s16x8*)(bA1 + roA + i * 1024);
#pragma unroll
        for (int i = 0; i < 4; ++i) fpB[i] = *(const s16x8*)(bP1 + roP + i * 1024);
        if (kt + 2 < NT) STAGE_A(kt + 2);
        __builtin_amdgcn_sched_barrier(0);
        __builtin_amdgcn_s_setprio(1);
        MFMA8(accB, fX1, fpA, 2);
        __builtin_amdgcn_s_setprio(0);
        __builtin_amdgcn_s_barrier();

        // -------- phase 3: accA x kh1 (uses fX0, fpB) --------
        LGKM0_FENCE();
        __builtin_amdgcn_s_setprio(1);
        MFMA8(accA, fX0, fpB, 0);
        __builtin_amdgcn_s_setprio(0);
        __builtin_amdgcn_sched_barrier(0);
        if (kt < NT - 2) asm volatile("s_waitcnt vmcnt(6)" ::: "memory");
        else             asm volatile("s_waitcnt vmcnt(0)" ::: "memory");
#pragma unroll
        for (int i = 0; i < 4; ++i) fX1[i] = *(const s16x8*)(bB1 + roA + i * 1024);
        if (kt + 2 < NT) STAGE_B(kt + 2);
        __builtin_amdgcn_sched_barrier(0);
        __builtin_amdgcn_s_setprio(1);
        MFMA8(accA, fX0, fpB, 2);
        __builtin_amdgcn_s_setprio(0);
        __builtin_amdgcn_s_barrier();

        // -------- phase 4: accB x kh1 (uses fX1, fpB) --------
        LGKM0_FENCE();
        __builtin_amdgcn_s_setprio(1);
        MFMA8(accB, fX1, fpB, 0);
        __builtin_amdgcn_s_setprio(0);
        __builtin_amdgcn_sched_barrier(0);
#pragma unroll
        for (int i = 0; i < 4; ++i) fX0[i] = *(const s16x8*)(nA0 + roA + i * 1024);
#pragma unroll
        for (int i = 0; i < 4; ++i) fpA[i] = *(const s16x8*)(nP0 + roP + i * 1024);
        if (kt + 2 < NT) STAGE_C(kt + 2);
        __builtin_amdgcn_sched_barrier(0);
        __builtin_amdgcn_s_setprio(1);
        MFMA8(accB, fX1, fpB, 2);
        __builtin_amdgcn_s_setprio(0);
        __builtin_amdgcn_s_barrier();
    }

    // epilogue: out = c0 + cA*A + cB*B + cAB*A*B
#pragma unroll
    for (int mi = 0; mi < 4; ++mi) {
#pragma unroll
        for (int i = 0; i < 4; ++i) {
            const int row = m0 + wr * 64 + mi * 16 + lq * 4 + i;
            const float4 c = C4[row];
#pragma unroll
            for (int ni = 0; ni < 4; ++ni) {
                const int col = n0 + wc * 64 + ni * 16 + lr;
                const float Av = accA[mi][ni][i];
                const float Bv = accB[mi][ni][i];
                out[(size_t)row * N_DIM + col] = c.x + c.y * Av + c.z * Bv + c.w * Av * Bv;
            }
        }
    }
}

extern "C" void kernel_launch(void* const* d_in, const int* in_sizes, int n_in,
                              void* d_out, int out_size, void* d_ws, size_t ws_size,
                              hipStream_t stream) {
    const float* prev = (const float*)d_in[0];   // [2048][8192]
    const float* Wa   = (const float*)d_in[1];   // [2048][2048]
    const float* Wb   = (const float*)d_in[2];   // [2048][2048]
    const float* TW   = (const float*)d_in[3];   // [16][2048]
    float* out = (float*)d_out;                  // [2048][8192]

    char* ws = (char*)d_ws;
    ushort* Pa = (ushort*)(ws);                          //  8 MiB
    ushort* Pb = (ushort*)(ws + (size_t)(8u << 20));     //  8 MiB
    ushort* Pt = (ushort*)(ws + (size_t)(16u << 20));    // 32 MiB
    float4* C4 = (float4*)(ws + (size_t)(48u << 20));    // 32 KiB

    softmax_rows_kernel<<<dim3(2048, 2), 256, 0, stream>>>(Wa, Wb, Pa, Pb);
    table_c_kernel<<<dim3(8), 256, 0, stream>>>(TW, C4);
    transp_conv_kernel<<<dim3(N_DIM / 64, K_DIM / 64), 256, 0, stream>>>(prev, Pt);
    logic_gemm_kernel<<<dim3(N_DIM / BN, M_DIM / BM), 512, 0, stream>>>(Pa, Pb, Pt, C4, out);
}